// Round 1
// baseline (2382.324 us; speedup 1.0000x reference)
//
#include <hip/hip_runtime.h>
#include <hip/hip_bf16.h>

typedef unsigned short u16;
typedef __attribute__((ext_vector_type(8))) __bf16 bf16x8;
typedef __attribute__((ext_vector_type(4))) float f32x4;

// async global->LDS, 16B per lane; LDS dest is wave-uniform base + lane*16
#define GLDS16(gsrc, ldst)                                                         \
  __builtin_amdgcn_global_load_lds(                                               \
      (__attribute__((address_space(1))) const void*)(gsrc),                      \
      (__attribute__((address_space(3))) void*)(ldst), 16, 0, 0)

__device__ __forceinline__ float bf2f(u16 u) {
  union { unsigned int i; float f; } v; v.i = ((unsigned int)u) << 16; return v.f;
}
__device__ __forceinline__ u16 f2bf(float f) {
  union { float f; unsigned int i; } v; v.f = f;
  return (u16)((v.i + 0x7fffu + ((v.i >> 16) & 1u)) >> 16);  // RNE
}

// ---------------- f32 -> bf16 convert (x) ----------------
__global__ void cvt_x_kernel(const float4* __restrict__ in, ushort4* __restrict__ out) {
  size_t i = (size_t)blockIdx.x * 256 + threadIdx.x;
  float4 v = in[i];
  ushort4 o;
  o.x = f2bf(v.x); o.y = f2bf(v.y); o.z = f2bf(v.z); o.w = f2bf(v.w);
  out[i] = o;
}

// ---------------- transpose + convert: in f32 [R][C] -> out bf16 [C][R] ----------------
__global__ void tconv_kernel(const float* __restrict__ in, u16* __restrict__ out,
                             int R, int C) {
  __shared__ float tile[64][65];
  const int c0 = blockIdx.x * 64, r0 = blockIdx.y * 64;
  const int tx = threadIdx.x & 63, ty = threadIdx.x >> 6;  // ty 0..3
#pragma unroll
  for (int p = 0; p < 16; ++p) {
    int row = p * 4 + ty;
    tile[row][tx] = in[(size_t)(r0 + row) * C + c0 + tx];
  }
  __syncthreads();
#pragma unroll
  for (int p = 0; p < 16; ++p) {
    int row = p * 4 + ty;  // output row = input col
    out[(size_t)(c0 + row) * R + r0 + tx] = f2bf(tile[tx][row]);
  }
}

// ---------------- GEMM: C[M][N] = A[M][K] * BT[N][K]^T (bf16 in, f32 or bf16 out) ----
// m97 structure: 128x128 tile, BK=32, global_load_lds width 16, mfma 16x16x32 bf16.
__global__ __launch_bounds__(256, 2) void gemm_bt_kernel(
    const u16* __restrict__ A, const u16* __restrict__ BT,
    float* __restrict__ Cf, u16* __restrict__ Cb, int M, int N, int K) {
  __shared__ __align__(16) u16 As[128 * 32];
  __shared__ __align__(16) u16 Bs[128 * 32];
  const int tid = threadIdx.x;
  const int wave = tid >> 6, lane = tid & 63;
  const int quad = lane >> 4, l16 = lane & 15;
  const int m0 = blockIdx.y * 128, n0 = blockIdx.x * 128;
  const int wm = (wave >> 1) * 64, wn = (wave & 1) * 64;
  const int rck = lane >> 2;        // row within a 16-row staging chunk
  const int kc = (lane & 3) * 8;    // k-offset of this lane's 16B

  f32x4 acc[4][4] = {};

  const size_t a0 = (size_t)(m0 + 16 * wave + rck) * K;
  const size_t a1 = (size_t)(m0 + 16 * (wave + 4) + rck) * K;
  const size_t b0 = (size_t)(n0 + 16 * wave + rck) * K;
  const size_t b1 = (size_t)(n0 + 16 * (wave + 4) + rck) * K;

  for (int k0 = 0; k0 < K; k0 += 32) {
    __syncthreads();
    GLDS16(A + a0 + k0 + kc, As + 512 * wave);
    GLDS16(A + a1 + k0 + kc, As + 512 * (wave + 4));
    GLDS16(BT + b0 + k0 + kc, Bs + 512 * wave);
    GLDS16(BT + b1 + k0 + kc, Bs + 512 * (wave + 4));
    __syncthreads();
    bf16x8 af[4], bfr[4];
#pragma unroll
    for (int t = 0; t < 4; ++t)
      af[t] = *(const bf16x8*)(As + (wm + 16 * t + l16) * 32 + quad * 8);
#pragma unroll
    for (int t = 0; t < 4; ++t)
      bfr[t] = *(const bf16x8*)(Bs + (wn + 16 * t + l16) * 32 + quad * 8);
#pragma unroll
    for (int mt = 0; mt < 4; ++mt)
#pragma unroll
      for (int nt = 0; nt < 4; ++nt)
        acc[mt][nt] = __builtin_amdgcn_mfma_f32_16x16x32_bf16(af[mt], bfr[nt], acc[mt][nt], 0, 0, 0);
  }
  // C/D layout: col = lane&15 (n), row = quad*4 + r (m)
#pragma unroll
  for (int mt = 0; mt < 4; ++mt)
#pragma unroll
    for (int nt = 0; nt < 4; ++nt)
#pragma unroll
      for (int r = 0; r < 4; ++r) {
        int row = m0 + wm + 16 * mt + quad * 4 + r;
        int col = n0 + wn + 16 * nt + l16;
        float v = acc[mt][nt][r];
        if (Cb) Cb[(size_t)row * N + col] = f2bf(v);
        else    Cf[(size_t)row * N + col] = v;
      }
}

// ---------------- RoPE in-place on q (heads 0..39) and k (heads 40..49) ----------------
__global__ void rope_kernel(u16* __restrict__ qkv, const int* __restrict__ positions) {
  int idx = blockIdx.x * 256 + threadIdx.x;  // 8192*64
  int j = idx & 63, t = idx >> 6;
  // inv_freq = 10000^(-j/64) = 2^(-j * log2(10000)/64)
  float inv = exp2f(-(float)j * 0.20762050593046014f);
  float ang = (float)positions[t] * inv;
  float sn, cs;
  sincosf(ang, &sn, &cs);
  u16* row = qkv + (size_t)t * 7680;
#pragma unroll 2
  for (int h = 0; h < 50; ++h) {
    u16* p1 = row + h * 128 + j;
    float x1 = bf2f(p1[0]), x2 = bf2f(p1[64]);
    p1[0] = f2bf(x1 * cs - x2 * sn);
    p1[64] = f2bf(x2 * cs + x1 * sn);
  }
}

// ---------------- V transpose: qkv v-part [t][kvh][d] -> VT[b][kvh][d][s] ----------------
__global__ void vtrans_kernel(const u16* __restrict__ qkv, u16* __restrict__ vt) {
  __shared__ u16 tile[64][132];
  const int s0 = blockIdx.x * 64, kvh = blockIdx.y, b = blockIdx.z;
  const int tid = threadIdx.x;
#pragma unroll
  for (int p = 0; p < 8; ++p) {
    int sl = p * 8 + (tid >> 5);
    int d = (tid & 31) * 4;
    const u16* src = qkv + (size_t)(b * 1024 + s0 + sl) * 7680 + (50 + kvh) * 128 + d;
    ushort4 v = *(const ushort4*)src;
    tile[sl][d] = v.x; tile[sl][d + 1] = v.y; tile[sl][d + 2] = v.z; tile[sl][d + 3] = v.w;
  }
  __syncthreads();
#pragma unroll
  for (int p = 0; p < 8; ++p) {
    int d = p * 16 + (tid >> 4);
    int sl = (tid & 15) * 4;
    ushort4 v;
    v.x = tile[sl][d]; v.y = tile[sl + 1][d]; v.z = tile[sl + 2][d]; v.w = tile[sl + 3][d];
    u16* dst = vt + ((size_t)((b * 10 + kvh) * 128) + d) * 1024 + s0 + sl;
    *(ushort4*)dst = v;
  }
}

// ---------------- flash attention, causal, GQA 4:1 ----------------
// block = (q_tile 128, head, batch); 4 waves, each owns 32 q rows.
__global__ __launch_bounds__(256, 2) void attn_kernel(
    const u16* __restrict__ qkv, const u16* __restrict__ vt, u16* __restrict__ ao) {
  // K tile 64s x 128d as 4 sub-tiles [64][32] (64B rows -> conflict-free ds_read_b128)
  __shared__ __align__(16) u16 Ks[4][2048];
  // V^T tile 128d x 64s as 2 sub-tiles [128][32]
  __shared__ __align__(16) u16 VTs[2][4096];
  // P per wave: 32q x 64s as 2 sub-tiles [32][32]
  __shared__ __align__(16) u16 Ps[4][2][1024];

  const int tid = threadIdx.x, wave = tid >> 6, lane = tid & 63;
  const int quad = lane >> 4, l16 = lane & 15;
  const int q0 = blockIdx.x * 128, h = blockIdx.y, b = blockIdx.z;
  const int kvh = h >> 2;
  const float SCALE = 0.08838834764831845f;  // 1/sqrt(128)

  // Q fragments in registers: A-operand layout A[m=lane&15][k=quad*8+j]
  bf16x8 qf[2][4];
#pragma unroll
  for (int mt = 0; mt < 2; ++mt) {
    int t = b * 1024 + q0 + wave * 32 + mt * 16 + l16;
    const u16* qrow = qkv + (size_t)t * 7680 + h * 128;
#pragma unroll
    for (int ks = 0; ks < 4; ++ks)
      qf[mt][ks] = *(const bf16x8*)(qrow + ks * 32 + quad * 8);
  }

  f32x4 oa[2][8] = {};
  float mstate[2][4], lstate[2][4];
#pragma unroll
  for (int mt = 0; mt < 2; ++mt)
#pragma unroll
    for (int r = 0; r < 4; ++r) { mstate[mt][r] = -1e30f; lstate[mt][r] = 0.f; }

  const u16* Kbase = qkv + (size_t)(b * 1024) * 7680 + (40 + kvh) * 128;
  const u16* VTbase = vt + (size_t)((b * 10 + kvh) * 128) * 1024;

  const int nsteps = q0 / 64 + 2;
  for (int step = 0; step < nsteps; ++step) {
    const int s0 = step * 64;
    __syncthreads();  // previous iteration's LDS reads done
#pragma unroll
    for (int j = 0; j < 4; ++j) {
      int c = 4 * wave + j;
      int ksub = c >> 2, rg = c & 3;
      GLDS16(Kbase + (size_t)(s0 + rg * 16 + (lane >> 2)) * 7680 + ksub * 32 + (lane & 3) * 8,
             &Ks[ksub][rg * 512]);
      int vsub = c >> 3, dg = c & 7;
      GLDS16(VTbase + (size_t)(dg * 16 + (lane >> 2)) * 1024 + s0 + vsub * 32 + (lane & 3) * 8,
             &VTs[vsub][dg * 512]);
    }
    __syncthreads();  // staging visible (vmcnt drained by barrier)

    // S = Q K^T  (rows m=q, cols n=s)
    f32x4 sa[2][4] = {};
#pragma unroll
    for (int ks = 0; ks < 4; ++ks) {
      bf16x8 kb[4];
#pragma unroll
      for (int nt = 0; nt < 4; ++nt)
        kb[nt] = *(const bf16x8*)&Ks[ks][(nt * 16 + l16) * 32 + quad * 8];
#pragma unroll
      for (int mt = 0; mt < 2; ++mt)
#pragma unroll
        for (int nt = 0; nt < 4; ++nt)
          sa[mt][nt] = __builtin_amdgcn_mfma_f32_16x16x32_bf16(qf[mt][ks], kb[nt], sa[mt][nt], 0, 0, 0);
    }

    // online softmax per q row (rows live in C-layout: row = quad*4+r)
#pragma unroll
    for (int mt = 0; mt < 2; ++mt) {
#pragma unroll
      for (int r = 0; r < 4; ++r) {
        int qg = q0 + wave * 32 + mt * 16 + quad * 4 + r;
        float pv[4];
        float rowmax = -1e30f;
#pragma unroll
        for (int nt = 0; nt < 4; ++nt) {
          int sg = s0 + nt * 16 + l16;
          float v = sa[mt][nt][r] * SCALE;
          if (sg > qg) v = -1e30f;
          pv[nt] = v;
          rowmax = fmaxf(rowmax, v);
        }
#pragma unroll
        for (int off = 1; off < 16; off <<= 1)
          rowmax = fmaxf(rowmax, __shfl_xor(rowmax, off));
        float mnew = fmaxf(mstate[mt][r], rowmax);
        float alpha = __expf(mstate[mt][r] - mnew);
        mstate[mt][r] = mnew;
        float rs = 0.f;
#pragma unroll
        for (int nt = 0; nt < 4; ++nt) {
          float p = __expf(pv[nt] - mnew);
          rs += p;
          Ps[wave][nt >> 1][(mt * 16 + quad * 4 + r) * 32 + (nt & 1) * 16 + l16] = f2bf(p);
        }
#pragma unroll
        for (int off = 1; off < 16; off <<= 1)
          rs += __shfl_xor(rs, off);
        lstate[mt][r] = lstate[mt][r] * alpha + rs;
#pragma unroll
        for (int ntd = 0; ntd < 8; ++ntd) oa[mt][ntd][r] *= alpha;
      }
    }
    __syncthreads();  // P writes visible

    // O += P V  (A = P[q][s], B = V[s][d] read from VT sub-tiles)
#pragma unroll
    for (int ks2 = 0; ks2 < 2; ++ks2) {
      bf16x8 pf[2];
#pragma unroll
      for (int mt = 0; mt < 2; ++mt)
        pf[mt] = *(const bf16x8*)&Ps[wave][ks2][(mt * 16 + l16) * 32 + quad * 8];
#pragma unroll
      for (int ntd = 0; ntd < 8; ++ntd) {
        bf16x8 vf = *(const bf16x8*)&VTs[ks2][(ntd * 16 + l16) * 32 + quad * 8];
#pragma unroll
        for (int mt = 0; mt < 2; ++mt)
          oa[mt][ntd] = __builtin_amdgcn_mfma_f32_16x16x32_bf16(pf[mt], vf, oa[mt][ntd], 0, 0, 0);
      }
    }
  }

  // epilogue: O / l -> ao[t][h][d] bf16
#pragma unroll
  for (int mt = 0; mt < 2; ++mt)
#pragma unroll
    for (int ntd = 0; ntd < 8; ++ntd)
#pragma unroll
      for (int r = 0; r < 4; ++r) {
        int t = b * 1024 + q0 + wave * 32 + mt * 16 + quad * 4 + r;
        int d = ntd * 16 + l16;
        float v = oa[mt][ntd][r] / lstate[mt][r];
        ao[((size_t)t * 40 + h) * 128 + d] = f2bf(v);
      }
}

// ---------------- launch ----------------
extern "C" void kernel_launch(void* const* d_in, const int* in_sizes, int n_in,
                              void* d_out, int out_size, void* d_ws, size_t ws_size,
                              hipStream_t stream) {
  const float* x = (const float*)d_in[0];
  const float* wqkv = (const float*)d_in[1];
  const float* wo = (const float*)d_in[2];
  const int* pos = (const int*)d_in[3];
  float* out = (float*)d_out;

  char* ws = (char*)d_ws;
  // layout (bytes): xb 83,886,080 (reused as attn-out) | wT 78,643,200 (reused as woT)
  //                 | qkv 125,829,120 | vt 20,971,520  => total 309,329,920
  u16* xb = (u16*)(ws);
  u16* wT = (u16*)(ws + 83886080);
  u16* qkvb = (u16*)(ws + 83886080 + 78643200);
  u16* vt = (u16*)(ws + 83886080 + 78643200 + 125829120);

  cvt_x_kernel<<<40960, 256, 0, stream>>>((const float4*)x, (ushort4*)xb);
  tconv_kernel<<<dim3(120, 80), 256, 0, stream>>>(wqkv, wT, 5120, 7680);
  gemm_bt_kernel<<<dim3(60, 64), 256, 0, stream>>>(xb, wT, nullptr, qkvb, 8192, 7680, 5120);
  rope_kernel<<<2048, 256, 0, stream>>>(qkvb, pos);
  vtrans_kernel<<<dim3(16, 10, 8), 256, 0, stream>>>(qkvb, vt);
  tconv_kernel<<<dim3(80, 80), 256, 0, stream>>>(wo, wT, 5120, 5120);  // wT now = w_o^T
  attn_kernel<<<dim3(8, 40, 8), 256, 0, stream>>>(qkvb, vt, xb);       // xb now = attn out
  gemm_bt_kernel<<<dim3(40, 64), 256, 0, stream>>>(xb, wT, out, nullptr, 8192, 5120, 5120);
}

// Round 2
// 2332.060 us; speedup vs baseline: 1.0216x; 1.0216x over previous
//
#include <hip/hip_runtime.h>
#include <hip/hip_bf16.h>

typedef unsigned short u16;
typedef __attribute__((ext_vector_type(8))) __bf16 bf16x8;
typedef __attribute__((ext_vector_type(4))) float f32x4;

// async global->LDS, 16B per lane; LDS dest is wave-uniform base + lane*16
#define GLDS16(gsrc, ldst)                                                         \
  __builtin_amdgcn_global_load_lds(                                               \
      (__attribute__((address_space(1))) const void*)(gsrc),                      \
      (__attribute__((address_space(3))) void*)(ldst), 16, 0, 0)

__device__ __forceinline__ float bf2f(u16 u) {
  union { unsigned int i; float f; } v; v.i = ((unsigned int)u) << 16; return v.f;
}
__device__ __forceinline__ u16 f2bf(float f) {
  union { float f; unsigned int i; } v; v.f = f;
  return (u16)((v.i + 0x7fffu + ((v.i >> 16) & 1u)) >> 16);  // RNE
}

// ---------------- f32 -> bf16 convert (x) ----------------
__global__ void cvt_x_kernel(const float4* __restrict__ in, ushort4* __restrict__ out) {
  size_t i = (size_t)blockIdx.x * 256 + threadIdx.x;
  float4 v = in[i];
  ushort4 o;
  o.x = f2bf(v.x); o.y = f2bf(v.y); o.z = f2bf(v.z); o.w = f2bf(v.w);
  out[i] = o;
}

// ---------------- transpose + convert: in f32 [R][C] -> out bf16 [C][R] ----------------
__global__ void tconv_kernel(const float* __restrict__ in, u16* __restrict__ out,
                             int R, int C) {
  __shared__ float tile[64][65];
  const int c0 = blockIdx.x * 64, r0 = blockIdx.y * 64;
  const int tx = threadIdx.x & 63, ty = threadIdx.x >> 6;  // ty 0..3
#pragma unroll
  for (int p = 0; p < 16; ++p) {
    int row = p * 4 + ty;
    tile[row][tx] = in[(size_t)(r0 + row) * C + c0 + tx];
  }
  __syncthreads();
#pragma unroll
  for (int p = 0; p < 16; ++p) {
    int row = p * 4 + ty;  // output row = input col
    out[(size_t)(c0 + row) * R + r0 + tx] = f2bf(tile[tx][row]);
  }
}

// ---------------- GEMM: C[M][N] = A[M][K] * BT[N][K]^T (bf16 in, f32 or bf16 out) ----
// m97 structure: 128x128 tile, BK=32, global_load_lds width 16, mfma 16x16x32 bf16.
// 1D grid with panel swizzle: panels of PW n-tiles x (M/128) m-tiles so the
// ~512 concurrently-resident blocks share a small B working set (L2/L3 reuse).
__global__ __launch_bounds__(256, 2) void gemm_bt_kernel(
    const u16* __restrict__ A, const u16* __restrict__ BT,
    float* __restrict__ Cf, u16* __restrict__ Cb, int M, int N, int K,
    int nbx, int nby) {
  const int PW = 8;
  const int per_panel = nby * PW;
  const int bid = blockIdx.x;
  const int panel = bid / per_panel;
  const int rem = bid - panel * per_panel;
  const int pw = min(PW, nbx - panel * PW);
  const int bn = panel * PW + rem % pw;
  const int bm = rem / pw;

  __shared__ __align__(16) u16 As[128 * 32];
  __shared__ __align__(16) u16 Bs[128 * 32];
  const int tid = threadIdx.x;
  const int wave = tid >> 6, lane = tid & 63;
  const int quad = lane >> 4, l16 = lane & 15;
  const int m0 = bm * 128, n0 = bn * 128;
  const int wm = (wave >> 1) * 64, wn = (wave & 1) * 64;
  const int rck = lane >> 2;        // row within a 16-row staging chunk
  const int kc = (lane & 3) * 8;    // k-offset of this lane's 16B

  f32x4 acc[4][4] = {};

  const size_t a0 = (size_t)(m0 + 16 * wave + rck) * K;
  const size_t a1 = (size_t)(m0 + 16 * (wave + 4) + rck) * K;
  const size_t b0 = (size_t)(n0 + 16 * wave + rck) * K;
  const size_t b1 = (size_t)(n0 + 16 * (wave + 4) + rck) * K;

  for (int k0 = 0; k0 < K; k0 += 32) {
    __syncthreads();
    GLDS16(A + a0 + k0 + kc, As + 512 * wave);
    GLDS16(A + a1 + k0 + kc, As + 512 * (wave + 4));
    GLDS16(BT + b0 + k0 + kc, Bs + 512 * wave);
    GLDS16(BT + b1 + k0 + kc, Bs + 512 * (wave + 4));
    __syncthreads();
    bf16x8 af[4], bfr[4];
#pragma unroll
    for (int t = 0; t < 4; ++t)
      af[t] = *(const bf16x8*)(As + (wm + 16 * t + l16) * 32 + quad * 8);
#pragma unroll
    for (int t = 0; t < 4; ++t)
      bfr[t] = *(const bf16x8*)(Bs + (wn + 16 * t + l16) * 32 + quad * 8);
#pragma unroll
    for (int mt = 0; mt < 4; ++mt)
#pragma unroll
      for (int nt = 0; nt < 4; ++nt)
        acc[mt][nt] = __builtin_amdgcn_mfma_f32_16x16x32_bf16(af[mt], bfr[nt], acc[mt][nt], 0, 0, 0);
  }
  // C/D layout: col = lane&15 (n), row = quad*4 + r (m)
#pragma unroll
  for (int mt = 0; mt < 4; ++mt)
#pragma unroll
    for (int nt = 0; nt < 4; ++nt)
#pragma unroll
      for (int r = 0; r < 4; ++r) {
        int row = m0 + wm + 16 * mt + quad * 4 + r;
        int col = n0 + wn + 16 * nt + l16;
        float v = acc[mt][nt][r];
        if (Cb) Cb[(size_t)row * N + col] = f2bf(v);
        else    Cf[(size_t)row * N + col] = v;
      }
}

// ---------------- RoPE in-place on q (heads 0..39) and k (heads 40..49) ----------------
__global__ void rope_kernel(u16* __restrict__ qkv, const int* __restrict__ positions) {
  int idx = blockIdx.x * 256 + threadIdx.x;  // 8192*64
  int j = idx & 63, t = idx >> 6;
  // inv_freq = 10000^(-j/64) = 2^(-j * log2(10000)/64)
  float inv = exp2f(-(float)j * 0.20762050593046014f);
  float ang = (float)positions[t] * inv;
  float sn, cs;
  sincosf(ang, &sn, &cs);
  u16* row = qkv + (size_t)t * 7680;
#pragma unroll 2
  for (int h = 0; h < 50; ++h) {
    u16* p1 = row + h * 128 + j;
    float x1 = bf2f(p1[0]), x2 = bf2f(p1[64]);
    p1[0] = f2bf(x1 * cs - x2 * sn);
    p1[64] = f2bf(x2 * cs + x1 * sn);
  }
}

// ---------------- V transpose: qkv v-part [t][kvh][d] -> VT[b][kvh][d][s] ----------------
__global__ void vtrans_kernel(const u16* __restrict__ qkv, u16* __restrict__ vt) {
  __shared__ u16 tile[64][132];
  const int s0 = blockIdx.x * 64, kvh = blockIdx.y, b = blockIdx.z;
  const int tid = threadIdx.x;
#pragma unroll
  for (int p = 0; p < 8; ++p) {
    int sl = p * 8 + (tid >> 5);
    int d = (tid & 31) * 4;
    const u16* src = qkv + (size_t)(b * 1024 + s0 + sl) * 7680 + (50 + kvh) * 128 + d;
    ushort4 v = *(const ushort4*)src;
    tile[sl][d] = v.x; tile[sl][d + 1] = v.y; tile[sl][d + 2] = v.z; tile[sl][d + 3] = v.w;
  }
  __syncthreads();
#pragma unroll
  for (int p = 0; p < 8; ++p) {
    int d = p * 16 + (tid >> 4);
    int sl = (tid & 15) * 4;
    ushort4 v;
    v.x = tile[sl][d]; v.y = tile[sl + 1][d]; v.z = tile[sl + 2][d]; v.w = tile[sl + 3][d];
    u16* dst = vt + ((size_t)((b * 10 + kvh) * 128) + d) * 1024 + s0 + sl;
    *(ushort4*)dst = v;
  }
}

// ---------------- flash attention, causal, GQA 4:1 ----------------
// block = (q_tile 128, head, batch); 4 waves, each owns 32 q rows.
__global__ __launch_bounds__(256, 2) void attn_kernel(
    const u16* __restrict__ qkv, const u16* __restrict__ vt, u16* __restrict__ ao) {
  // K tile 64s x 128d as 4 sub-tiles [64][32] (64B rows -> conflict-free ds_read_b128)
  __shared__ __align__(16) u16 Ks[4][2048];
  // V^T tile 128d x 64s as 2 sub-tiles [128][32]
  __shared__ __align__(16) u16 VTs[2][4096];
  // P per wave: 32q x 64s as 2 sub-tiles [32][32]
  __shared__ __align__(16) u16 Ps[4][2][1024];

  const int tid = threadIdx.x, wave = tid >> 6, lane = tid & 63;
  const int quad = lane >> 4, l16 = lane & 15;
  const int q0 = blockIdx.x * 128, h = blockIdx.y, b = blockIdx.z;
  const int kvh = h >> 2;
  const float SCALE = 0.08838834764831845f;  // 1/sqrt(128)

  // Q fragments in registers: A-operand layout A[m=lane&15][k=quad*8+j]
  bf16x8 qf[2][4];
#pragma unroll
  for (int mt = 0; mt < 2; ++mt) {
    int t = b * 1024 + q0 + wave * 32 + mt * 16 + l16;
    const u16* qrow = qkv + (size_t)t * 7680 + h * 128;
#pragma unroll
    for (int ks = 0; ks < 4; ++ks)
      qf[mt][ks] = *(const bf16x8*)(qrow + ks * 32 + quad * 8);
  }

  f32x4 oa[2][8] = {};
  float mstate[2][4], lstate[2][4];
#pragma unroll
  for (int mt = 0; mt < 2; ++mt)
#pragma unroll
    for (int r = 0; r < 4; ++r) { mstate[mt][r] = -1e30f; lstate[mt][r] = 0.f; }

  const u16* Kbase = qkv + (size_t)(b * 1024) * 7680 + (40 + kvh) * 128;
  const u16* VTbase = vt + (size_t)((b * 10 + kvh) * 128) * 1024;

  const int nsteps = q0 / 64 + 2;
  for (int step = 0; step < nsteps; ++step) {
    const int s0 = step * 64;
    __syncthreads();  // previous iteration's LDS reads done
#pragma unroll
    for (int j = 0; j < 4; ++j) {
      int c = 4 * wave + j;
      int ksub = c >> 2, rg = c & 3;
      GLDS16(Kbase + (size_t)(s0 + rg * 16 + (lane >> 2)) * 7680 + ksub * 32 + (lane & 3) * 8,
             &Ks[ksub][rg * 512]);
      int vsub = c >> 3, dg = c & 7;
      GLDS16(VTbase + (size_t)(dg * 16 + (lane >> 2)) * 1024 + s0 + vsub * 32 + (lane & 3) * 8,
             &VTs[vsub][dg * 512]);
    }
    __syncthreads();  // staging visible (vmcnt drained by barrier)

    // S = Q K^T  (rows m=q, cols n=s)
    f32x4 sa[2][4] = {};
#pragma unroll
    for (int ks = 0; ks < 4; ++ks) {
      bf16x8 kb[4];
#pragma unroll
      for (int nt = 0; nt < 4; ++nt)
        kb[nt] = *(const bf16x8*)&Ks[ks][(nt * 16 + l16) * 32 + quad * 8];
#pragma unroll
      for (int mt = 0; mt < 2; ++mt)
#pragma unroll
        for (int nt = 0; nt < 4; ++nt)
          sa[mt][nt] = __builtin_amdgcn_mfma_f32_16x16x32_bf16(qf[mt][ks], kb[nt], sa[mt][nt], 0, 0, 0);
    }

    // online softmax per q row (rows live in C-layout: row = quad*4+r)
#pragma unroll
    for (int mt = 0; mt < 2; ++mt) {
#pragma unroll
      for (int r = 0; r < 4; ++r) {
        int qg = q0 + wave * 32 + mt * 16 + quad * 4 + r;
        float pv[4];
        float rowmax = -1e30f;
#pragma unroll
        for (int nt = 0; nt < 4; ++nt) {
          int sg = s0 + nt * 16 + l16;
          float v = sa[mt][nt][r] * SCALE;
          if (sg > qg) v = -1e30f;
          pv[nt] = v;
          rowmax = fmaxf(rowmax, v);
        }
#pragma unroll
        for (int off = 1; off < 16; off <<= 1)
          rowmax = fmaxf(rowmax, __shfl_xor(rowmax, off));
        float mnew = fmaxf(mstate[mt][r], rowmax);
        float alpha = __expf(mstate[mt][r] - mnew);
        mstate[mt][r] = mnew;
        float rs = 0.f;
#pragma unroll
        for (int nt = 0; nt < 4; ++nt) {
          float p = __expf(pv[nt] - mnew);
          rs += p;
          Ps[wave][nt >> 1][(mt * 16 + quad * 4 + r) * 32 + (nt & 1) * 16 + l16] = f2bf(p);
        }
#pragma unroll
        for (int off = 1; off < 16; off <<= 1)
          rs += __shfl_xor(rs, off);
        lstate[mt][r] = lstate[mt][r] * alpha + rs;
#pragma unroll
        for (int ntd = 0; ntd < 8; ++ntd) oa[mt][ntd][r] *= alpha;
      }
    }
    __syncthreads();  // P writes visible

    // O += P V  (A = P[q][s], B = V[s][d] read from VT sub-tiles)
#pragma unroll
    for (int ks2 = 0; ks2 < 2; ++ks2) {
      bf16x8 pf[2];
#pragma unroll
      for (int mt = 0; mt < 2; ++mt)
        pf[mt] = *(const bf16x8*)&Ps[wave][ks2][(mt * 16 + l16) * 32 + quad * 8];
#pragma unroll
      for (int ntd = 0; ntd < 8; ++ntd) {
        bf16x8 vf = *(const bf16x8*)&VTs[ks2][(ntd * 16 + l16) * 32 + quad * 8];
#pragma unroll
        for (int mt = 0; mt < 2; ++mt)
          oa[mt][ntd] = __builtin_amdgcn_mfma_f32_16x16x32_bf16(pf[mt], vf, oa[mt][ntd], 0, 0, 0);
      }
    }
  }

  // epilogue: O / l -> ao[t][h][d] bf16
#pragma unroll
  for (int mt = 0; mt < 2; ++mt)
#pragma unroll
    for (int ntd = 0; ntd < 8; ++ntd)
#pragma unroll
      for (int r = 0; r < 4; ++r) {
        int t = b * 1024 + q0 + wave * 32 + mt * 16 + quad * 4 + r;
        int d = ntd * 16 + l16;
        float v = oa[mt][ntd][r] / lstate[mt][r];
        ao[((size_t)t * 40 + h) * 128 + d] = f2bf(v);
      }
}

// ---------------- launch ----------------
extern "C" void kernel_launch(void* const* d_in, const int* in_sizes, int n_in,
                              void* d_out, int out_size, void* d_ws, size_t ws_size,
                              hipStream_t stream) {
  const float* x = (const float*)d_in[0];
  const float* wqkv = (const float*)d_in[1];
  const float* wo = (const float*)d_in[2];
  const int* pos = (const int*)d_in[3];
  float* out = (float*)d_out;

  char* ws = (char*)d_ws;
  // layout (bytes): xb 83,886,080 (reused as attn-out) | wT 78,643,200 (reused as woT)
  //                 | qkv 125,829,120 | vt 20,971,520  => total 309,329,920
  u16* xb = (u16*)(ws);
  u16* wT = (u16*)(ws + 83886080);
  u16* qkvb = (u16*)(ws + 83886080 + 78643200);
  u16* vt = (u16*)(ws + 83886080 + 78643200 + 125829120);

  cvt_x_kernel<<<40960, 256, 0, stream>>>((const float4*)x, (ushort4*)xb);
  tconv_kernel<<<dim3(120, 80), 256, 0, stream>>>(wqkv, wT, 5120, 7680);
  gemm_bt_kernel<<<60 * 64, 256, 0, stream>>>(xb, wT, nullptr, qkvb, 8192, 7680, 5120, 60, 64);
  rope_kernel<<<2048, 256, 0, stream>>>(qkvb, pos);
  vtrans_kernel<<<dim3(16, 10, 8), 256, 0, stream>>>(qkvb, vt);
  tconv_kernel<<<dim3(80, 80), 256, 0, stream>>>(wo, wT, 5120, 5120);  // wT now = w_o^T
  attn_kernel<<<dim3(8, 40, 8), 256, 0, stream>>>(qkvb, vt, xb);       // xb now = attn out
  gemm_bt_kernel<<<40 * 64, 256, 0, stream>>>(xb, wT, out, nullptr, 8192, 5120, 5120, 40, 64);
}